// Round 1
// baseline (642.741 us; speedup 1.0000x reference)
//
#include <hip/hip_runtime.h>
#include <cstdint>
#include <cstddef>

#define HH 96
#define WW 96
#define NN 8
#define CIN 512
#define CMID 256
#define CO2 576

typedef __attribute__((ext_vector_type(4))) float f32x4;
typedef __attribute__((ext_vector_type(8))) short short8;

static __device__ __forceinline__ unsigned short f2bf(float f) {
    unsigned int u = __float_as_uint(f);
    u += 0x7fffu + ((u >> 16) & 1u);
    return (unsigned short)(u >> 16);
}

// w1 (256,512,3,3) OIHW fp32 -> w1t [9][256][512] bf16 ; w2 (576,256) -> bf16
__global__ __launch_bounds__(256) void prep_w_kernel(
    const float* __restrict__ w1, const float* __restrict__ w2,
    unsigned short* __restrict__ w1t, unsigned short* __restrict__ w2t)
{
    size_t i = (size_t)blockIdx.x * 256 + threadIdx.x;
    if (i < (size_t)9 * CMID * CIN) {
        int tap = (int)(i / (CMID * CIN));
        int r   = (int)(i % (CMID * CIN));
        int co = r / CIN, ci = r % CIN;
        w1t[i] = f2bf(w1[((size_t)co * CIN + ci) * 9 + tap]);
    }
    if (i < (size_t)CO2 * CMID) {
        w2t[i] = f2bf(w2[i]);
    }
}

// feature (N,512,96,96) fp32 -> featT [N][H][W][512] bf16
__global__ __launch_bounds__(256) void transpose_kernel(
    const float* __restrict__ f, unsigned short* __restrict__ ft)
{
    __shared__ float t[96 * 65];
    const int tid = threadIdx.x;
    const int b = blockIdx.x;
    const int n = b / HH, h = b % HH;
    for (int cb = 0; cb < 8; ++cb) {
        __syncthreads();
        #pragma unroll
        for (int it = 0; it < 24; ++it) {
            int idx = tid + it * 256;          // 0..6143
            int cl = idx / 96, w = idx - cl * 96;
            t[w * 65 + cl] = f[(((size_t)n * CIN + cb * 64 + cl) * HH + h) * WW + w];
        }
        __syncthreads();
        #pragma unroll
        for (int it = 0; it < 24; ++it) {
            int idx = tid + it * 256;
            int w = idx >> 6, cl = idx & 63;
            ft[(((size_t)n * HH + h) * WW + w) * CIN + cb * 64 + cl] = f2bf(t[w * 65 + cl]);
        }
    }
}

// conv1: 3x3, 512->256, bias+ReLU. One block per (n,h). x out: [N][H][W][256] bf16
__global__ __launch_bounds__(256) void conv1_kernel(
    const unsigned short* __restrict__ featT,
    const unsigned short* __restrict__ w1t,
    const float* __restrict__ b1,
    unsigned short* __restrict__ x)
{
    __shared__ unsigned short fs[3 * 98 * 64];   // [row][w+1][ci64], XOR-swizzled
    const int tid = threadIdx.x;
    const int b = blockIdx.x;
    const int n = b / HH, h = b % HH;
    const int wave = tid >> 6, lane = tid & 63;
    const int g = lane >> 4, sl = lane & 15;

    f32x4 acc[6][4];
    #pragma unroll
    for (int i = 0; i < 6; ++i)
        #pragma unroll
        for (int j = 0; j < 4; ++j) acc[i][j] = (f32x4)0.0f;

    for (int cb = 0; cb < 8; ++cb) {
        __syncthreads();
        #pragma unroll
        for (int it = 0; it < 9; ++it) {
            int idx = tid + it * 256;            // 0..2303
            int r = idx / 768;
            int pos = idx - r * 768;
            int w = pos >> 3, ci8 = pos & 7;
            int hh2 = h + r - 1;
            int lw = w + 1;
            int off = r * (98 * 64) + lw * 64 + ((ci8 ^ (lw & 7)) << 3);
            short8 v = (short8)0;
            if ((unsigned)hh2 < HH) {
                v = *reinterpret_cast<const short8*>(
                    &featT[(((size_t)n * HH + hh2) * WW + w) * CIN + cb * 64 + ci8 * 8]);
            }
            *reinterpret_cast<short8*>(&fs[off]) = v;
        }
        if (tid < 48) {                           // zero pad columns lw=0, lw=97
            int r = tid >> 4;
            int c2 = (tid >> 3) & 1;
            int ci8 = tid & 7;
            int lw = c2 ? 97 : 0;
            int off = r * (98 * 64) + lw * 64 + ((ci8 ^ (lw & 7)) << 3);
            *reinterpret_cast<short8*>(&fs[off]) = (short8)0;
        }
        __syncthreads();

        #pragma unroll
        for (int ki = 0; ki < 3; ++ki) {
            #pragma unroll
            for (int kj = 0; kj < 3; ++kj) {
                const int tap = ki * 3 + kj;
                #pragma unroll
                for (int kc = 0; kc < 2; ++kc) {
                    short8 af[4];
                    const unsigned short* ab =
                        &w1t[(size_t)tap * CMID * CIN + (size_t)(cb * 64 + kc * 32 + g * 8)];
                    #pragma unroll
                    for (int tc = 0; tc < 4; ++tc) {
                        int co = wave * 64 + tc * 16 + sl;
                        af[tc] = *reinterpret_cast<const short8*>(&ab[(size_t)co * CIN]);
                    }
                    #pragma unroll
                    for (int ts = 0; ts < 6; ++ts) {
                        int lw = ts * 16 + sl + kj;
                        int off = ki * (98 * 64) + lw * 64 + (((kc * 4 + g) ^ (lw & 7)) << 3);
                        short8 bf = *reinterpret_cast<const short8*>(&fs[off]);
                        #pragma unroll
                        for (int tc = 0; tc < 4; ++tc) {
                            acc[ts][tc] = __builtin_amdgcn_mfma_f32_16x16x32_bf16(
                                af[tc], bf, acc[ts][tc], 0, 0, 0);
                        }
                    }
                }
            }
        }
    }

    // epilogue: bias + ReLU -> bf16 x[n][h][w][co]
    const size_t rowbase = ((size_t)n * HH + h);
    #pragma unroll
    for (int ts = 0; ts < 6; ++ts) {
        int s = ts * 16 + sl;
        unsigned short* xp = &x[(rowbase * WW + s) * CMID];
        #pragma unroll
        for (int tc = 0; tc < 4; ++tc) {
            int co0 = wave * 64 + tc * 16 + g * 4;
            const float4 bb = *reinterpret_cast<const float4*>(&b1[co0]);
            float v0 = acc[ts][tc][0] + bb.x;
            float v1 = acc[ts][tc][1] + bb.y;
            float v2 = acc[ts][tc][2] + bb.z;
            float v3 = acc[ts][tc][3] + bb.w;
            v0 = v0 > 0.f ? v0 : 0.f;
            v1 = v1 > 0.f ? v1 : 0.f;
            v2 = v2 > 0.f ? v2 : 0.f;
            v3 = v3 > 0.f ? v3 : 0.f;
            ushort4 st;
            st.x = f2bf(v0); st.y = f2bf(v1); st.z = f2bf(v2); st.w = f2bf(v3);
            *reinterpret_cast<ushort4*>(&xp[co0]) = st;
        }
    }
}

// conv2 (1x1, 256->576) + bias*0.25 + softmax over 9 taps + flow assembly
// One block per (n,h). 6 waves x 16 spatial each, all 576 co per wave.
__global__ __launch_bounds__(384) void conv2_kernel(
    const unsigned short* __restrict__ x,
    const unsigned short* __restrict__ w2t,
    const float* __restrict__ b2,
    const float* __restrict__ flow,
    float* __restrict__ out)
{
    __shared__ float lo[16 * 768];
    const int tid = threadIdx.x;
    const int b = blockIdx.x;
    const int n = b / HH, h = b % HH;
    const int wave = tid >> 6, lane = tid & 63;
    const int g = lane >> 4, sl = lane & 15;
    const int s = wave * 16 + sl;

    f32x4 acc[36];
    #pragma unroll
    for (int i = 0; i < 36; ++i) acc[i] = (f32x4)0.0f;

    const unsigned short* xrow = &x[(((size_t)n * HH + h) * WW) * CMID];
    #pragma unroll
    for (int kc = 0; kc < 8; ++kc) {
        short8 bf = *reinterpret_cast<const short8*>(&xrow[s * CMID + kc * 32 + g * 8]);
        #pragma unroll
        for (int tc = 0; tc < 36; ++tc) {
            short8 af = *reinterpret_cast<const short8*>(
                &w2t[(size_t)(tc * 16 + sl) * CMID + kc * 32 + g * 8]);
            acc[tc] = __builtin_amdgcn_mfma_f32_16x16x32_bf16(af, bf, acc[tc], 0, 0, 0);
        }
    }

    // bias + 0.25 scale
    #pragma unroll
    for (int tc = 0; tc < 36; ++tc) {
        const float4 bb = *reinterpret_cast<const float4*>(&b2[tc * 16 + g * 4]);
        acc[tc][0] = 0.25f * (acc[tc][0] + bb.x);
        acc[tc][1] = 0.25f * (acc[tc][1] + bb.y);
        acc[tc][2] = 0.25f * (acc[tc][2] + bb.z);
        acc[tc][3] = 0.25f * (acc[tc][3] + bb.w);
    }

    // 8*flow 3x3 neighborhood (zero-padded)
    float pf[2][9];
    #pragma unroll
    for (int ch = 0; ch < 2; ++ch) {
        #pragma unroll
        for (int ki = 0; ki < 3; ++ki) {
            #pragma unroll
            for (int kj = 0; kj < 3; ++kj) {
                int hh2 = h + ki - 1, ww2 = s + kj - 1;
                float v = 0.f;
                if ((unsigned)hh2 < HH && (unsigned)ww2 < WW)
                    v = flow[(((size_t)n * 2 + ch) * HH + hh2) * WW + ww2];
                pf[ch][ki * 3 + kj] = 8.f * v;
            }
        }
    }

    // lane-local softmax over k for each of the 16 pp values this lane owns
    #pragma unroll
    for (int mp = 0; mp < 4; ++mp) {
        #pragma unroll
        for (int i = 0; i < 4; ++i) {
            int pp = mp * 16 + g * 4 + i;
            float L[9];
            #pragma unroll
            for (int k = 0; k < 9; ++k) L[k] = acc[mp + 4 * k][i];
            float mx = L[0];
            #pragma unroll
            for (int k = 1; k < 9; ++k) mx = fmaxf(mx, L[k]);
            float e[9], sum = 0.f;
            #pragma unroll
            for (int k = 0; k < 9; ++k) { e[k] = __expf(L[k] - mx); sum += e[k]; }
            float inv = 1.f / sum;
            int py = pp >> 3, px = pp & 7;
            #pragma unroll
            for (int ch = 0; ch < 2; ++ch) {
                float o = 0.f;
                #pragma unroll
                for (int k = 0; k < 9; ++k) o += e[k] * pf[ch][k];
                lo[(ch * 8 + py) * 768 + s * 8 + px] = o * inv;
            }
        }
    }
    __syncthreads();

    // coalesced output: 16 rows of 768 floats
    #pragma unroll
    for (int it = 0; it < 8; ++it) {
        int idx = tid + it * 384;               // float4 index, 0..3071
        int row = idx / 192, c4 = idx - row * 192;
        int ch = row >> 3, py = row & 7;
        float4 v = *reinterpret_cast<const float4*>(&lo[row * 768 + c4 * 4]);
        *reinterpret_cast<float4*>(
            &out[(((size_t)n * 2 + ch) * 768 + h * 8 + py) * 768 + c4 * 4]) = v;
    }
}

extern "C" void kernel_launch(void* const* d_in, const int* in_sizes, int n_in,
                              void* d_out, int out_size, void* d_ws, size_t ws_size,
                              hipStream_t stream)
{
    const float* feature = (const float*)d_in[0];
    const float* flow    = (const float*)d_in[1];
    const float* w1      = (const float*)d_in[2];
    const float* b1      = (const float*)d_in[3];
    const float* w2      = (const float*)d_in[4];
    const float* b2      = (const float*)d_in[5];
    float* out = (float*)d_out;

    const size_t featT_bytes = (size_t)NN * HH * WW * CIN * 2;   // 75,497,472
    const size_t x_bytes     = (size_t)NN * HH * WW * CMID * 2;  // 37,748,736
    const size_t w1t_bytes   = (size_t)9 * CMID * CIN * 2;       //  2,359,296
    const size_t w2t_bytes   = (size_t)CO2 * CMID * 2;           //    294,912
    if (ws_size < featT_bytes + x_bytes + w1t_bytes + w2t_bytes) return;

    char* ws = (char*)d_ws;
    unsigned short* featT = (unsigned short*)ws;
    unsigned short* xbuf  = (unsigned short*)(ws + featT_bytes);
    unsigned short* w1t   = (unsigned short*)(ws + featT_bytes + x_bytes);
    unsigned short* w2t   = (unsigned short*)(ws + featT_bytes + x_bytes + w1t_bytes);

    prep_w_kernel<<<4608, 256, 0, stream>>>(w1, w2, w1t, w2t);
    transpose_kernel<<<NN * HH, 256, 0, stream>>>(feature, featT);
    conv1_kernel<<<NN * HH, 256, 0, stream>>>(featT, w1t, b1, xbuf);
    conv2_kernel<<<NN * HH, 384, 0, stream>>>(xbuf, w2t, b2, flow, out);
}